// Round 11
// baseline (39.727 us; speedup 1.0000x reference)
//
#include <hip/hip_runtime.h>
#include <hip/hip_bf16.h>

using f32x4  = __attribute__((ext_vector_type(4))) float;
using bf16x8 = __attribute__((ext_vector_type(8))) short;

constexpr int N_ = 512;
constexpr int K_ = 512;
constexpr int BM = 256, BN = 128, BK = 32;
constexpr int LDSK = 36;      // 32 + 4 pad (stride 18 dwords -> 16 distinct banks)
constexpr int NKS = K_ / BK;  // 16

__device__ inline ushort f2bf(float f) {
  union { __hip_bfloat16 h; ushort u; } c;
  c.h = __float2bfloat16(f);
  return c.u;
}

// r3/r10 champion schedule (dbuf, 2-deep reg prefetch, 1 __syncthreads/K-step)
// at 256x128 tile: half the blocks per CU (half the pipeline ramps), 25% less
// staging work per MFMA, 2 blocks/CU via 55.3 KB LDS, 3 waves/SIMD.
__global__ __launch_bounds__(512, 3)
void gemm_bf16_kernel(const float* __restrict__ X, const float* __restrict__ W,
                      float* __restrict__ C) {
  __shared__ ushort As[2][BM * LDSK];   // 2 x 18.4 KB
  __shared__ ushort Bs[2][BN * LDSK];   // 2 x 9.2 KB

  const int t    = threadIdx.x;
  const int lane = t & 63;
  const int wave = t >> 6;      // 0..7
  const int wr   = wave >> 1;   // 0..3 -> 64-row slab
  const int wc   = wave & 1;    // 0..1 -> 64-col slab

  // XCD-aware bijective swizzle (512 blocks = 8 XCDs x 64): the 4 bn-tiles of
  // each x row-panel are consecutive on one XCD -> x re-reads are L2/L3 hits.
  const int cpx = gridDim.x >> 3;
  const int bid = (blockIdx.x & 7) * cpx + (blockIdx.x >> 3);
  const int bn  = bid & 3;
  const int bm  = bid >> 2;
  const int m0 = bm * BM, n0 = bn * BN;

  // staging map: 512 threads cover 64 rows x 32 cols (f32x4) per slab
  const int sr = t >> 3;        // 0..63
  const int sc = (t & 7) * 4;   // 0,4,...,28

  const float* xp = X + (size_t)(m0 + sr) * K_ + sc;
  const float* wp = W + (size_t)(n0 + sr) * K_ + sc;

  f32x4 acc[4][4] = {};
  f32x4 ra[2][4], rb[2][2];     // 2-deep prefetch

  auto LOAD = [&](int set, int ks) {
#pragma unroll
    for (int i = 0; i < 4; ++i)
      ra[set][i] = *reinterpret_cast<const f32x4*>(xp + (size_t)(i * 64) * K_ + ks * BK);
#pragma unroll
    for (int i = 0; i < 2; ++i)
      rb[set][i] = *reinterpret_cast<const f32x4*>(wp + (size_t)(i * 64) * K_ + ks * BK);
  };

  auto STAGE = [&](int set, int buf) {   // counted vmcnt wait on ra/rb[set] only
#pragma unroll
    for (int i = 0; i < 4; ++i) {
      ushort4 h;
      h.x = f2bf(ra[set][i].x); h.y = f2bf(ra[set][i].y);
      h.z = f2bf(ra[set][i].z); h.w = f2bf(ra[set][i].w);
      *reinterpret_cast<ushort4*>(&As[buf][(sr + 64 * i) * LDSK + sc]) = h;
    }
#pragma unroll
    for (int i = 0; i < 2; ++i) {
      ushort4 h;
      h.x = f2bf(rb[set][i].x); h.y = f2bf(rb[set][i].y);
      h.z = f2bf(rb[set][i].z); h.w = f2bf(rb[set][i].w);
      *reinterpret_cast<ushort4*>(&Bs[buf][(sr + 64 * i) * LDSK + sc]) = h;
    }
  };

  auto MMA = [&](int buf) {
    const int kof = (lane >> 4) * 8;
    bf16x8 a[4], b[4];
#pragma unroll
    for (int mi = 0; mi < 4; ++mi)
      a[mi] = *reinterpret_cast<const bf16x8*>(
          &As[buf][(wr * 64 + mi * 16 + (lane & 15)) * LDSK + kof]);
#pragma unroll
    for (int ni = 0; ni < 4; ++ni)
      b[ni] = *reinterpret_cast<const bf16x8*>(
          &Bs[buf][(wc * 64 + ni * 16 + (lane & 15)) * LDSK + kof]);
#pragma unroll
    for (int mi = 0; mi < 4; ++mi)
#pragma unroll
      for (int ni = 0; ni < 4; ++ni)
        acc[mi][ni] = __builtin_amdgcn_mfma_f32_16x16x32_bf16(a[mi], b[ni],
                                                              acc[mi][ni], 0, 0, 0);
  };

  // ---- prologue: loads for ks=0,1 in flight; stage ks=0 into buf0 ----
  LOAD(0, 0);
  LOAD(1, 1);
  STAGE(0, 0);
  __syncthreads();

  // ---- main loop: 1 barrier per K-step; 2-deep prefetch ----
#pragma unroll
  for (int ks = 0; ks < NKS - 1; ++ks) {
    if (ks + 2 < NKS) LOAD(ks & 1, ks + 2);   // issue 2 steps ahead
    MMA(ks & 1);                               // compute current
    STAGE((ks + 1) & 1, (ks + 1) & 1);         // waits loads issued 1 iter ago
    __syncthreads();
  }
  MMA((NKS - 1) & 1);

  // ---- store: C/D layout col = lane&15, row = (lane>>4)*4 + reg ----
  const int col0 = n0 + wc * 64 + (lane & 15);
  const int rsub = (lane >> 4) * 4;
#pragma unroll
  for (int mi = 0; mi < 4; ++mi)
#pragma unroll
    for (int ni = 0; ni < 4; ++ni)
#pragma unroll
      for (int r = 0; r < 4; ++r)
        C[(size_t)(m0 + wr * 64 + mi * 16 + rsub + r) * N_ + (col0 + ni * 16)] =
            acc[mi][ni][r];
}

extern "C" void kernel_launch(void* const* d_in, const int* in_sizes, int n_in,
                              void* d_out, int out_size, void* d_ws, size_t ws_size,
                              hipStream_t stream) {
  const float* x = (const float*)d_in[0];
  const float* w = (const float*)d_in[1];
  float* out = (float*)d_out;
  const int M = in_sizes[0] / K_;            // 32768
  dim3 grid((M / BM) * (N_ / BN));           // 128 * 4 = 512 blocks
  gemm_bf16_kernel<<<grid, dim3(512), 0, stream>>>(x, w, out);
}